// Round 2
// baseline (1904.824 us; speedup 1.0000x reference)
//
#include <hip/hip_runtime.h>
#include <math.h>

// ---------------- scan / CSR build ----------------

__global__ void k_count(const int* __restrict__ dst, int* __restrict__ counts, int E){
  int e = blockIdx.x*256 + threadIdx.x;
  if (e < E) atomicAdd(&counts[dst[e]], 1);
}

__global__ void k_scan1(const int* __restrict__ cnt, int* __restrict__ excl,
                        int* __restrict__ bsum, int N){
  __shared__ int sm[1024];
  int tid = threadIdx.x, gid = blockIdx.x*1024 + tid;
  int v = (gid < N) ? cnt[gid] : 0;
  sm[tid] = v; __syncthreads();
  for (int off=1; off<1024; off<<=1){
    int t = (tid >= off) ? sm[tid-off] : 0;
    __syncthreads();
    sm[tid] += t;
    __syncthreads();
  }
  if (gid < N) excl[gid] = sm[tid] - v;
  if (tid == 1023) bsum[blockIdx.x] = sm[tid];
}

__global__ void k_scan2(int* __restrict__ bsum, int NB){
  __shared__ int sm[1024];
  int tid = threadIdx.x;
  int v = (tid < NB) ? bsum[tid] : 0;
  sm[tid] = v; __syncthreads();
  for (int off=1; off<1024; off<<=1){
    int t = (tid >= off) ? sm[tid-off] : 0;
    __syncthreads();
    sm[tid] += t;
    __syncthreads();
  }
  if (tid < NB) bsum[tid] = sm[tid] - v;
}

__global__ void k_scan3(const int* __restrict__ excl, const int* __restrict__ bsum,
                        int* __restrict__ offsets, int* __restrict__ cursor, int N, int E){
  int gid = blockIdx.x*1024 + threadIdx.x;
  if (gid < N){ int o = excl[gid] + bsum[gid>>10]; offsets[gid] = o; cursor[gid] = o; }
  if (gid == N) offsets[N] = E;
}

__global__ void k_geom(const int* __restrict__ esrc, const int* __restrict__ edst,
                       int* __restrict__ cursor, int* __restrict__ csr_src,
                       int* __restrict__ csr_eid, int E){
  int e = blockIdx.x*256 + threadIdx.x;
  if (e >= E) return;
  int d = edst[e];
  int p = atomicAdd(&cursor[d], 1);
  csr_src[p] = esrc[e];
  csr_eid[p] = e;
}

// ---------------- per-layer: geometry + radial MLP -> shw (CSR-ordered) ----------------

__global__ __launch_bounds__(256) void k_shw(
    const int* __restrict__ esrc, const int* __restrict__ edst,
    const int* __restrict__ csr_eid,
    const float* __restrict__ pos, const int* __restrict__ types,
    const float* __restrict__ embed,
    const float* __restrict__ w1, const float* __restrict__ w2,
    float* __restrict__ shw, int E){
  __shared__ float sEmb[16];
  __shared__ float sW1[180];
  __shared__ float sW2[90];
  int t = threadIdx.x;
  if (t < 16) sEmb[t] = embed[t];
  if (t < 180) sW1[t] = w1[t];
  if (t < 90)  sW2[t] = w2[t];
  __syncthreads();
  int p = blockIdx.x*256 + t;
  if (p >= E) return;
  int e = csr_eid[p];
  int s = esrc[e], d = edst[e];
  float px = pos[3*d]-pos[3*s], py = pos[3*d+1]-pos[3*s+1], pz = pos[3*d+2]-pos[3*s+2];
  float r = sqrtf(px*px + py*py + pz*pz);
  float rm = fmaxf(r, 1e-9f);
  float inv = 1.f/rm;
  float ux = px*inv, uy = py*inv, uz = pz*inv;
  const float c1 = 1.7320508075688772f, c2 = 3.872983346207417f, c2b = 1.118033988749895f;
  float sh[9];
  sh[0]=1.f; sh[1]=c1*uy; sh[2]=c1*uz; sh[3]=c1*ux;
  sh[4]=c2*ux*uy; sh[5]=c2*uy*uz; sh[6]=c2b*(3.f*uz*uz-1.f); sh[7]=c2*ux*uz;
  sh[8]=0.5f*c2*(ux*ux-uy*uy);
  float ee[18];
  int ts_ = types[s], td_ = types[d];
  #pragma unroll
  for (int i=0;i<4;i++){ ee[i] = sEmb[td_*4+i]; ee[4+i] = sEmb[ts_*4+i]; }
  float xx = r * 0.2f;                    // r / CUTOFF
  float x2v = xx*xx, x3v = x2v*xx, x6 = x3v*x3v, x7 = x6*xx, x8 = x7*xx;
  float env = 1.f - 28.f*x6 + 48.f*x7 - 21.f*x8;
  const float bc = 0.6324555320336759f;   // sqrt(2/5)
  float pref = bc * env * inv;
  const float PI = 3.14159265358979323846f;
  #pragma unroll
  for (int n=1;n<=10;n++) ee[7+n] = pref * __sinf(PI * (float)n * xx);

  float h[10];
  #pragma unroll
  for (int j=0;j<10;j++){
    float a = 0.f;
    #pragma unroll
    for (int k=0;k<18;k++) a = fmaf(ee[k], sW1[k*10+j], a);
    h[j] = fmaxf(a, 0.f);
  }
  #pragma unroll
  for (int sj=0;sj<9;sj++){
    float a = 0.f;
    #pragma unroll
    for (int j=0;j<10;j++) a = fmaf(h[j], sW2[j*9+sj], a);
    shw[(size_t)p*9+sj] = sh[sj]*a;
  }
}

// ---------------- layer 1: thread-per-dest (Z is 36 regs) + gate + residual ----------------

__global__ __launch_bounds__(256) void k_layer1(
    const int* __restrict__ offsets, const int* __restrict__ csr_src,
    const float* __restrict__ shw1, const int* __restrict__ types,
    const float* __restrict__ embed, const float* __restrict__ tp1,
    float* __restrict__ x1, int N){
  __shared__ float sT[36*92];
  __shared__ float sEmb[16];
  int t = threadIdx.x;
  if (t < 16) sEmb[t] = embed[t];
  for (int i=t; i<36*92; i+=256) sT[i] = tp1[i]*0.25f;   // fold 1/sqrt(AVG_DEG)
  __syncthreads();
  int d = blockIdx.x*256 + t;
  if (d >= N) return;
  float Z[36];
  #pragma unroll
  for (int i=0;i<36;i++) Z[i]=0.f;
  int b0 = offsets[d], b1 = offsets[d+1];
  for (int j=b0;j<b1;j++){
    int sn = csr_src[j];
    int tt = types[sn];
    float x0[4];
    #pragma unroll
    for (int i=0;i<4;i++) x0[i] = sEmb[tt*4+i];
    #pragma unroll
    for (int si=0;si<9;si++){
      float sw = shw1[(size_t)j*9+si];
      #pragma unroll
      for (int i=0;i<4;i++) Z[si*4+i] = fmaf(sw, x0[i], Z[si*4+i]);
    }
  }
  float sact[12];
  #pragma unroll
  for (int c=0;c<12;c++){
    float y=0.f;
    #pragma unroll
    for (int p=0;p<36;p++) y = fmaf(Z[p], sT[p*92+c], y);
    sact[c] = (c<4) ? fmaxf(y,0.f) : fabsf(y);
  }
  float gact[16];
  #pragma unroll
  for (int c=0;c<16;c++){
    float y=0.f;
    #pragma unroll
    for (int p=0;p<36;p++) y = fmaf(Z[p], sT[p*92+12+c], y);
    gact[c] = (c<4 || (c>=8 && c<12)) ? fmaxf(y,0.f) : tanhf(y);
  }
  int td = types[d];
  float* xo = x1 + (size_t)d*76;
  #pragma unroll
  for (int c=0;c<12;c++) xo[c] = sact[c] + (c<4 ? sEmb[td*4+c] : 0.f);
  #pragma unroll
  for (int j=0;j<64;j++){
    float y=0.f;
    #pragma unroll
    for (int p=0;p<36;p++) y = fmaf(Z[p], sT[p*92+28+j], y);
    int gi = (j<24) ? (j/3) : (8 + (j-24)/5);
    xo[12+j] = y*gact[gi];
  }
}

// ---------------- layer 2 stage A: wave-per-dest Z accumulation (lane = feature) ----------------

__global__ __launch_bounds__(256) void k_conv2(
    const int* __restrict__ offsets, const int* __restrict__ csr_src,
    const float* __restrict__ shw2, const float* __restrict__ x1,
    float* __restrict__ Z2, int d0, int dend){
  int lane = threadIdx.x & 63;
  int d = d0 + blockIdx.x*4 + (threadIdx.x >> 6);
  if (d >= dend) return;
  float z[9], zb[9];
  #pragma unroll
  for (int s=0;s<9;s++){ z[s]=0.f; zb[s]=0.f; }
  bool hi = lane < 12;
  int b0 = offsets[d], b1 = offsets[d+1];
  for (int j=b0;j<b1;j++){
    int sn = csr_src[j];                       // wave-uniform
    const float* xr = x1 + (size_t)sn*76;
    float xa = xr[lane];
    float xb = hi ? xr[64+lane] : 0.f;
    #pragma unroll
    for (int s=0;s<9;s++){
      float sw = shw2[(size_t)j*9+s];          // wave-uniform broadcast
      z[s]  = fmaf(sw, xa, z[s]);
      zb[s] = fmaf(sw, xb, zb[s]);
    }
  }
  float* zr = Z2 + (size_t)(d - d0)*704;
  #pragma unroll
  for (int s=0;s<9;s++){
    zr[s*76+lane] = z[s];
    if (hi) zr[s*76+64+lane] = zb[s];
  }
  if (lane < 20) zr[684+lane] = 0.f;           // K padding 684->704
}

// ---------------- layer 2 stage B: (chunk x 704) @ (704 x 96) GEMM + gate + residual ----------------

__global__ void k_wprep(const float* __restrict__ tp2, float* __restrict__ W){
  int q = blockIdx.x*256 + threadIdx.x;
  if (q >= 704*96) return;
  int k = q/96, f = q - 96*k;
  W[q] = (k < 684 && f < 92) ? tp2[k*92+f]*0.25f : 0.f;
}

__global__ __launch_bounds__(256) void k_gemm2(
    const float* __restrict__ Z2, const float* __restrict__ W,
    const float* __restrict__ x1, float* __restrict__ x2, int d0, int dend){
  __shared__ float lz[64][68];
  __shared__ float lw[64][100];
  int t = threadIdx.x;
  int mb = blockIdx.x*64;          // row within chunk
  int m0 = d0 + mb;                // global node
  int tf = t & 31, tg = t >> 5;
  float acc[8][3];
  #pragma unroll
  for (int a=0;a<8;a++)
    #pragma unroll
    for (int b=0;b<3;b++) acc[a][b]=0.f;
  for (int c=0;c<11;c++){
    #pragma unroll
    for (int j=0;j<4;j++){
      int q = j*256+t; int m = q>>4, k4 = q&15;
      *(float4*)&lz[m][k4*4] = *(const float4*)&Z2[(size_t)(mb+m)*704 + c*64 + k4*4];
    }
    #pragma unroll
    for (int j=0;j<6;j++){
      int q = j*256+t; int k = q/24, f4 = q - k*24;
      *(float4*)&lw[k][f4*4] = *(const float4*)&W[(size_t)(c*64+k)*96 + f4*4];
    }
    __syncthreads();
    #pragma unroll 2
    for (int kk=0; kk<64; kk+=4){
      float av[8][4];
      #pragma unroll
      for (int mi=0;mi<8;mi++) *(float4*)av[mi] = *(const float4*)&lz[tg*8+mi][kk];
      #pragma unroll
      for (int u=0;u<4;u++){
        #pragma unroll
        for (int fj=0;fj<3;fj++){
          float bv = lw[kk+u][tf*3+fj];
          #pragma unroll
          for (int mi=0;mi<8;mi++) acc[mi][fj] = fmaf(av[mi][u], bv, acc[mi][fj]);
        }
      }
    }
    __syncthreads();
  }
  // stage conv-out tile into lw (done with weights)
  #pragma unroll
  for (int mi=0;mi<8;mi++)
    #pragma unroll
    for (int fj=0;fj<3;fj++)
      lw[tg*8+mi][tf*3+fj] = acc[mi][fj];
  __syncthreads();
  int m = t>>2, q = t&3;
  int node = m0 + m;
  if (node < dend){
    const float* xr = x1 + (size_t)node*76;
    float* xo = x2 + (size_t)node*76;
    for (int cc=q*19; cc<q*19+19; cc++){
      float v;
      if (cc < 12){
        float y = lw[m][cc];
        v = (cc<4) ? fmaxf(y,0.f) : fabsf(y);
      } else {
        int j = cc-12;
        int gi = (j<24) ? (j/3) : (8 + (j-24)/5);
        float gy = lw[m][12+gi];
        float ga = (gi<4 || (gi>=8 && gi<12)) ? fmaxf(gy,0.f) : tanhf(gy);
        v = lw[m][28+j]*ga;
      }
      xo[cc] = v + xr[cc];
    }
  }
}

// ---------------- layer 3: global sum collapses segment_sum -> per-edge dot + reduce ----------------

__global__ __launch_bounds__(256) void k_layer3(
    const int* __restrict__ csr_src, const float* __restrict__ shw3,
    const float* __restrict__ x2, const float* __restrict__ tp3,
    float* __restrict__ out, int E){
  __shared__ float tl[684];
  int t = threadIdx.x;
  for (int i=t;i<684;i+=256) tl[i] = tp3[i]*0.25f;
  __syncthreads();
  int e = blockIdx.x*256 + t;
  float part = 0.f;
  if (e < E){
    int sn = csr_src[e];
    const float* xr = x2 + (size_t)sn*76;
    float accs[9];
    #pragma unroll
    for (int s=0;s<9;s++) accs[s]=0.f;
    #pragma unroll
    for (int i4=0;i4<19;i4++){
      float4 xv = *(const float4*)&xr[i4*4];
      #pragma unroll
      for (int s=0;s<9;s++){
        const float* tp = &tl[s*76 + i4*4];
        accs[s] = fmaf(xv.x, tp[0], accs[s]);
        accs[s] = fmaf(xv.y, tp[1], accs[s]);
        accs[s] = fmaf(xv.z, tp[2], accs[s]);
        accs[s] = fmaf(xv.w, tp[3], accs[s]);
      }
    }
    float dots = 0.f;
    #pragma unroll
    for (int s=0;s<9;s++) dots = fmaf(accs[s], shw3[(size_t)e*9+s], dots);
    part = dots;
  }
  #pragma unroll
  for (int off=32; off>0; off>>=1) part += __shfl_down(part, off, 64);
  if ((t & 63) == 0) atomicAdd(out, part);
}

// ---------------- launch ----------------

extern "C" void kernel_launch(void* const* d_in, const int* in_sizes, int n_in,
                              void* d_out, int out_size, void* d_ws, size_t ws_size,
                              hipStream_t stream){
  const int*   types = (const int*)d_in[0];
  const float* pos   = (const float*)d_in[1];
  const int*   esrc  = (const int*)d_in[2];
  const int*   edst  = (const int*)d_in[3];
  const float* embed = (const float*)d_in[4];
  const float* m1w1=(const float*)d_in[5],  *m1w2=(const float*)d_in[6],  *tp1=(const float*)d_in[7];
  const float* m2w1=(const float*)d_in[8],  *m2w2=(const float*)d_in[9],  *tp2=(const float*)d_in[10];
  const float* m3w1=(const float*)d_in[11], *m3w2=(const float*)d_in[12], *tp3=(const float*)d_in[13];
  int N = in_sizes[0];
  int E = in_sizes[2];
  float* out = (float*)d_out;

  char* wsb = (char*)d_ws; size_t off = 0;
  auto alloc = [&](size_t b)->char*{ char* p = wsb + off; off = (off + b + 255) & ~(size_t)255; return p; };
  float* x1      = (float*)alloc((size_t)N*76*sizeof(float));
  float* x2      = (float*)alloc((size_t)N*76*sizeof(float));
  float* shw     = (float*)alloc((size_t)E*9*sizeof(float));   // reused for layers 1,2,3
  int*   csr_src = (int*)alloc((size_t)E*sizeof(int));
  int*   csr_eid = (int*)alloc((size_t)E*sizeof(int));
  int*   offsets = (int*)alloc((size_t)(N+1)*sizeof(int));
  int*   counts  = (int*)alloc((size_t)N*sizeof(int));
  int*   cursor  = (int*)alloc((size_t)N*sizeof(int));
  int*   excl    = (int*)alloc((size_t)N*sizeof(int));
  int*   bsum    = (int*)alloc(1024*sizeof(int));
  float* Wp      = (float*)alloc((size_t)704*96*sizeof(float));

  // elastic Z2 chunk: whatever workspace remains, capped, multiple of 64
  size_t avail = (ws_size > off) ? (ws_size - off - 512) : 0;
  long long rows = (long long)(avail / (704*sizeof(float))) - 64;
  int CH = (rows > 12544) ? 12544 : (int)rows;
  CH = (CH / 64) * 64;
  if (CH < 64) CH = 64;   // last resort; would need ~36 MB
  float* Z2 = (float*)alloc((size_t)(CH+64)*704*sizeof(float));

  hipMemsetAsync(counts, 0, (size_t)N*sizeof(int), stream);
  hipMemsetAsync(out, 0, sizeof(float), stream);

  int nbE = (E+255)/256;
  k_count<<<nbE,256,0,stream>>>(edst, counts, E);
  int NB1 = (N+1023)/1024;
  k_scan1<<<NB1,1024,0,stream>>>(counts, excl, bsum, N);
  k_scan2<<<1,1024,0,stream>>>(bsum, NB1);
  k_scan3<<<(N+1+1023)/1024,1024,0,stream>>>(excl, bsum, offsets, cursor, N, E);
  k_geom<<<nbE,256,0,stream>>>(esrc, edst, cursor, csr_src, csr_eid, E);
  k_wprep<<<(704*96+255)/256,256,0,stream>>>(tp2, Wp);

  // layer 1
  k_shw<<<nbE,256,0,stream>>>(esrc, edst, csr_eid, pos, types, embed, m1w1, m1w2, shw, E);
  k_layer1<<<(N+255)/256,256,0,stream>>>(offsets, csr_src, shw, types, embed, tp1, x1, N);

  // layer 2
  k_shw<<<nbE,256,0,stream>>>(esrc, edst, csr_eid, pos, types, embed, m2w1, m2w2, shw, E);
  for (int d0 = 0; d0 < N; d0 += CH){
    int dend = (d0 + CH < N) ? (d0 + CH) : N;
    int nn = dend - d0;
    k_conv2<<<(nn+3)/4,256,0,stream>>>(offsets, csr_src, shw, x1, Z2, d0, dend);
    k_gemm2<<<(nn+63)/64,256,0,stream>>>(Z2, Wp, x1, x2, d0, dend);
  }

  // layer 3
  k_shw<<<nbE,256,0,stream>>>(esrc, edst, csr_eid, pos, types, embed, m3w1, m3w2, shw, E);
  k_layer3<<<nbE,256,0,stream>>>(csr_src, shw, x2, tp3, out, E);
}